// Round 2
// baseline (1279.652 us; speedup 1.0000x reference)
//
#include <hip/hip_runtime.h>

#define CC 33
#define WAVE 64

__device__ __forceinline__ float wave_max64(float v) {
#pragma unroll
  for (int k = 32; k >= 1; k >>= 1) v = fmaxf(v, __shfl_xor(v, k, 64));
  return v;
}

__device__ __forceinline__ float wave_sum64(float v) {
#pragma unroll
  for (int k = 32; k >= 1; k >>= 1) v += __shfl_xor(v, k, 64);
  return v;
}

// One wave (64 lanes) per batch sequence. Lane j < 33 owns state j.
// Forward recurrence factored as:
//   next_alpha[j] = em[j] + m + log( sum_i exp(alpha[i]-m) * exp(trans[i][j]) )
// with exp(trans[i][j]) precomputed into per-lane registers (etcol[i] = etrans
// column j held by lane j). ealpha broadcast through LDS, read back as float4.
__global__ __launch_bounds__(WAVE) void crf_seq_kernel(
    const float* __restrict__ emissions, const int* __restrict__ tags,
    const int* __restrict__ mask, const float* __restrict__ transitions,
    const float* __restrict__ start_t, const float* __restrict__ end_t,
    const float* __restrict__ tmask, const float* __restrict__ smask,
    const float* __restrict__ emask, float* __restrict__ out_per_b, int T) {
  const int b = blockIdx.x;
  const int j = threadIdx.x;

  __shared__ float s_trans[CC * CC];
  __shared__ __align__(16) float s_e[WAVE];

  for (int k = j; k < CC * CC; k += WAVE) s_trans[k] = transitions[k] + tmask[k];
  __syncthreads();

  // lane j holds exp(trans[i][j]) for i=0..32; inactive lanes hold 0.
  float etcol[CC];
#pragma unroll
  for (int i = 0; i < CC; ++i)
    etcol[i] = (j < CC) ? __expf(s_trans[i * CC + j]) : 0.0f;

  const float* __restrict__ emb = emissions + (size_t)b * T * CC;
  const int* __restrict__ tagb = tags + (size_t)b * T;
  const int* __restrict__ maskb = mask + (size_t)b * T;

  const float NEG = -INFINITY;
  float endv = (j < CC) ? (end_t[j] + emask[j]) : NEG;
  float em0 = (j < CC) ? emb[j] : NEG;
  float alpha = ((j < CC) ? (start_t[j] + smask[j]) : NEG) + em0;

  int tag_prev = tagb[0];
  float score = __shfl(alpha, tag_prev, 64);  // start_s[tag0] + em0[tag0]
  int len = (maskb[0] != 0) ? 1 : 0;

  // prefetch state for step t=1
  float em_n = (j < CC) ? emb[CC + j] : NEG;
  int tag_n = tagb[1];
  int mt_n = (maskb[1] != 0) ? 1 : 0;

  for (int t = 1; t < T; ++t) {
    float emv = em_n;
    int cur = tag_n;
    int mt = mt_n;
    if (t + 1 < T) {
      em_n = (j < CC) ? emb[(size_t)(t + 1) * CC + j] : NEG;
      tag_n = tagb[t + 1];
      mt_n = (maskb[t + 1] != 0) ? 1 : 0;
    }

    // ---- logsumexp mat-vec ----
    float m = wave_max64(alpha);
    s_e[j] = __expf(alpha - m);  // lanes >= 33: exp(-inf)=0
    __builtin_amdgcn_wave_barrier();

    const float4* se4 = (const float4*)s_e;
    float a0 = 0.f, a1 = 0.f, a2 = 0.f, a3 = 0.f;
#pragma unroll
    for (int q = 0; q < 8; ++q) {
      float4 v = se4[q];
      a0 = fmaf(v.x, etcol[4 * q + 0], a0);
      a1 = fmaf(v.y, etcol[4 * q + 1], a1);
      a2 = fmaf(v.z, etcol[4 * q + 2], a2);
      a3 = fmaf(v.w, etcol[4 * q + 3], a3);
    }
    float s = ((a0 + a1) + (a2 + a3)) + s_e[32] * etcol[32];
    float anew = emv + m + __logf(s);
    alpha = mt ? anew : alpha;
    __builtin_amdgcn_wave_barrier();

    // ---- gold-path score (wave-uniform) ----
    float tsc = s_trans[tag_prev * CC + cur];  // uniform LDS read -> broadcast
    float esc = __shfl(emv, cur, 64);
    score += mt ? (tsc + esc) : 0.0f;
    len += mt;
    tag_prev = cur;
  }

  if (len < 1) len = 1;
  int last = tagb[len - 1];
  score += __shfl(endv, last, 64);

  // log_z = lse_j(alpha[j] + end_s[j])
  float v = (j < CC) ? (alpha + endv) : NEG;
  float m = wave_max64(v);
  float se = wave_sum64(__expf(v - m));
  float log_z = m + __logf(se);

  if (j == 0) out_per_b[b] = log_z - score;
}

__global__ __launch_bounds__(256) void reduce_mean_kernel(
    const float* __restrict__ v, float* __restrict__ out, int n) {
  int tid = threadIdx.x;
  float s = 0.f;
  for (int i = tid; i < n; i += 256) s += v[i];
  s = wave_sum64(s);
  __shared__ float ws[4];
  if ((tid & 63) == 0) ws[tid >> 6] = s;
  __syncthreads();
  if (tid == 0) out[0] = (ws[0] + ws[1] + ws[2] + ws[3]) / (float)n;
}

extern "C" void kernel_launch(void* const* d_in, const int* in_sizes, int n_in,
                              void* d_out, int out_size, void* d_ws, size_t ws_size,
                              hipStream_t stream) {
  const float* emissions = (const float*)d_in[0];
  const int* tags = (const int*)d_in[1];
  const int* mask = (const int*)d_in[2];
  const float* transitions = (const float*)d_in[3];
  const float* start_t = (const float*)d_in[4];
  const float* end_t = (const float*)d_in[5];
  const float* tmask = (const float*)d_in[6];
  const float* smask = (const float*)d_in[7];
  const float* emask = (const float*)d_in[8];

  const int T = 2048;                // fixed problem shape
  const int BT = in_sizes[1];        // B*T
  const int B = BT / T;
  float* per_b = (float*)d_ws;       // B floats of scratch

  crf_seq_kernel<<<B, WAVE, 0, stream>>>(emissions, tags, mask, transitions,
                                         start_t, end_t, tmask, smask, emask,
                                         per_b, T);
  reduce_mean_kernel<<<1, 256, 0, stream>>>(per_b, (float*)d_out, B);
}

// Round 3
// 481.212 us; speedup vs baseline: 2.6592x; 2.6592x over previous
//
#include <hip/hip_runtime.h>

#define CC 33
#define WAVE 64
#define PF 8  // prefetch depth == unroll factor

__device__ __forceinline__ float wave_sum64(float v) {
#pragma unroll
  for (int k = 32; k >= 1; k >>= 1) v += __shfl_xor(v, k, 64);
  return v;
}

__device__ __forceinline__ int wave_isum64(int v) {
#pragma unroll
  for (int k = 32; k >= 1; k >>= 1) v += __shfl_xor(v, k, 64);
  return v;
}

// broadcast lane `lane` (compile-time) of p to all lanes via v_readlane
__device__ __forceinline__ float rl(float v, int lane) {
  return __uint_as_float(__builtin_amdgcn_readlane(__float_as_uint(v), lane));
}

// ---------------------------------------------------------------------------
// Forward-algorithm scan, one wave per sequence, lane j owns state j.
// LINEAR-space recurrence: p_j <- (sum_i p_i * exp(trans[i][j])) * exp(em_j),
// renormalized by p[0] every 4 steps with log accumulated into `logoff`.
// alpha_j == log(p_j) + logoff at all times (shift-invariant, exact math).
// Emissions/mask prefetched PF=8 steps ahead into registers (raw em; the exp
// happens at consume time, parallel to the readlane/FMA chain).
// ---------------------------------------------------------------------------
__global__ __launch_bounds__(WAVE) void crf_scan_kernel(
    const float* __restrict__ emissions, const int* __restrict__ mask,
    const float* __restrict__ transitions, const float* __restrict__ start_t,
    const float* __restrict__ end_t, const float* __restrict__ tmask,
    const float* __restrict__ smask, const float* __restrict__ emask,
    float* __restrict__ logz_out, int T) {
  const int b = blockIdx.x;
  const int j = threadIdx.x;

  __shared__ float s_trans[CC * CC];
  for (int k = j; k < CC * CC; k += WAVE) s_trans[k] = transitions[k] + tmask[k];
  __syncthreads();

  // lane j holds exp(trans[i][j]) for all i (column j); lanes >= CC hold 0.
  float etcol[CC];
#pragma unroll
  for (int i = 0; i < CC; ++i)
    etcol[i] = (j < CC) ? __expf(s_trans[i * CC + j]) : 0.0f;

  const float* __restrict__ emb = emissions + (size_t)b * T * CC;
  const int* __restrict__ maskb = mask + (size_t)b * T;

  const float NEG = -INFINITY;
  // p = exp(alpha0); lanes >= CC stay exactly 0 forever.
  float p = (j < CC) ? __expf(start_t[j] + smask[j] + emb[j]) : 0.0f;
  float logoff = 0.0f;

  // prefetch ring: raw emission + mask for steps t0..t0+PF-1
  float em_pre[PF];
  int mc[PF];
#pragma unroll
  for (int k = 0; k < PF; ++k) {
    int t = 1 + k;
    int tc = t < T ? t : T - 1;
    em_pre[k] = (j < CC) ? emb[(size_t)tc * CC + j] : NEG;
    mc[k] = maskb[tc];
  }

  int t0 = 1;
  for (; t0 + PF <= T; t0 += PF) {
#pragma unroll
    for (int k = 0; k < PF; ++k) {
      float emk = em_pre[k];
      int mt = mc[k];
      // issue prefetch for t0+PF+k (consumed 8 steps later)
      {
        int tn = t0 + PF + k;
        int tc = tn < T ? tn : T - 1;
        em_pre[k] = (j < CC) ? emb[(size_t)tc * CC + j] : NEG;
        mc[k] = maskb[tc];
      }
      float eemk = __expf(emk);  // off the p-chain (dep: 8-steps-old load)

      // dot: s_j = sum_i p_i * etcol[i], broadcast via readlane
      float a0 = 0.f, a1 = 0.f, a2 = 0.f, a3 = 0.f;
#pragma unroll
      for (int i = 0; i < 32; i += 4) {
        a0 = fmaf(rl(p, i + 0), etcol[i + 0], a0);
        a1 = fmaf(rl(p, i + 1), etcol[i + 1], a1);
        a2 = fmaf(rl(p, i + 2), etcol[i + 2], a2);
        a3 = fmaf(rl(p, i + 3), etcol[i + 3], a3);
      }
      float s = ((a0 + a1) + (a2 + a3)) + rl(p, 32) * etcol[32];

      if ((k & 3) == 0) {
        // renormalize by previous p[0] (uniform), fold into the emission mul
        float r = rl(p, 0);
        float rs = __builtin_amdgcn_rcpf(r);
        float pn = s * (eemk * rs);
        p = mt ? pn : p;
        logoff += mt ? __logf(r) : 0.0f;
      } else {
        float pn = s * eemk;
        p = mt ? pn : p;
      }
    }
  }
  // tail (< PF steps), fully unrolled so slot indices stay compile-time
#pragma unroll
  for (int k = 0; k < PF; ++k) {
    if (t0 + k < T) {
      float emk = em_pre[k];
      int mt = mc[k];
      float eemk = __expf(emk);
      float a0 = 0.f, a1 = 0.f, a2 = 0.f, a3 = 0.f;
#pragma unroll
      for (int i = 0; i < 32; i += 4) {
        a0 = fmaf(rl(p, i + 0), etcol[i + 0], a0);
        a1 = fmaf(rl(p, i + 1), etcol[i + 1], a1);
        a2 = fmaf(rl(p, i + 2), etcol[i + 2], a2);
        a3 = fmaf(rl(p, i + 3), etcol[i + 3], a3);
      }
      float s = ((a0 + a1) + (a2 + a3)) + rl(p, 32) * etcol[32];
      if ((k & 3) == 0) {
        float r = rl(p, 0);
        float rs = __builtin_amdgcn_rcpf(r);
        float pn = s * (eemk * rs);
        p = mt ? pn : p;
        logoff += mt ? __logf(r) : 0.0f;
      } else {
        float pn = s * eemk;
        p = mt ? pn : p;
      }
    }
  }

  // log_z = logoff + log( sum_j p_j * exp(end_s_j) )
  float eend = (j < CC) ? __expf(end_t[j] + emask[j]) : 0.0f;
  float sum = wave_sum64(p * eend);
  if (j == 0) logz_out[b] = logoff + __logf(sum);
}

// ---------------------------------------------------------------------------
// Gold-path score: embarrassingly parallel over (b, t).
// ---------------------------------------------------------------------------
__global__ __launch_bounds__(256) void crf_score_kernel(
    const float* __restrict__ emissions, const int* __restrict__ tags,
    const int* __restrict__ mask, const float* __restrict__ transitions,
    const float* __restrict__ start_t, const float* __restrict__ end_t,
    const float* __restrict__ tmask, const float* __restrict__ smask,
    const float* __restrict__ emask, float* __restrict__ score_out, int T) {
  const int b = blockIdx.x;
  const int tid = threadIdx.x;

  __shared__ float s_trans[CC * CC];
  for (int k = tid; k < CC * CC; k += 256) s_trans[k] = transitions[k] + tmask[k];
  __syncthreads();

  const float* __restrict__ emb = emissions + (size_t)b * T * CC;
  const int* __restrict__ tagb = tags + (size_t)b * T;
  const int* __restrict__ maskb = mask + (size_t)b * T;

  float local = 0.f;
  int llen = 0;
  for (int t = tid; t < T; t += 256) {
    int mt = maskb[t];
    llen += (mt != 0);
    if (t >= 1) {
      int cur = tagb[t];
      int prev = tagb[t - 1];
      float v = s_trans[prev * CC + cur] + emb[(size_t)t * CC + cur];
      local += (mt != 0) ? v : 0.f;
    }
  }

  local = wave_sum64(local);
  llen = wave_isum64(llen);
  __shared__ float ws[4];
  __shared__ int wl[4];
  if ((tid & 63) == 0) { ws[tid >> 6] = local; wl[tid >> 6] = llen; }
  __syncthreads();
  if (tid == 0) {
    float total = ws[0] + ws[1] + ws[2] + ws[3];
    int len = wl[0] + wl[1] + wl[2] + wl[3];
    int tag0 = tagb[0];
    total += start_t[tag0] + smask[tag0] + emb[tag0];
    if (len < 1) len = 1;
    int last = tagb[len - 1];
    total += end_t[last] + emask[last];
    score_out[b] = total;
  }
}

__global__ __launch_bounds__(256) void reduce_mean_kernel(
    const float* __restrict__ logz, const float* __restrict__ score,
    float* __restrict__ out, int n) {
  int tid = threadIdx.x;
  float s = 0.f;
  for (int i = tid; i < n; i += 256) s += logz[i] - score[i];
  s = wave_sum64(s);
  __shared__ float ws[4];
  if ((tid & 63) == 0) ws[tid >> 6] = s;
  __syncthreads();
  if (tid == 0) out[0] = (ws[0] + ws[1] + ws[2] + ws[3]) / (float)n;
}

extern "C" void kernel_launch(void* const* d_in, const int* in_sizes, int n_in,
                              void* d_out, int out_size, void* d_ws, size_t ws_size,
                              hipStream_t stream) {
  const float* emissions = (const float*)d_in[0];
  const int* tags = (const int*)d_in[1];
  const int* mask = (const int*)d_in[2];
  const float* transitions = (const float*)d_in[3];
  const float* start_t = (const float*)d_in[4];
  const float* end_t = (const float*)d_in[5];
  const float* tmask = (const float*)d_in[6];
  const float* smask = (const float*)d_in[7];
  const float* emask = (const float*)d_in[8];

  const int T = 2048;          // fixed problem shape
  const int BT = in_sizes[1];  // B*T
  const int B = BT / T;

  float* logz = (float*)d_ws;       // B floats
  float* score = logz + B;          // B floats

  crf_scan_kernel<<<B, WAVE, 0, stream>>>(emissions, mask, transitions, start_t,
                                          end_t, tmask, smask, emask, logz, T);
  crf_score_kernel<<<B, 256, 0, stream>>>(emissions, tags, mask, transitions,
                                          start_t, end_t, tmask, smask, emask,
                                          score, T);
  reduce_mean_kernel<<<1, 256, 0, stream>>>(logz, score, (float*)d_out, B);
}